// Round 6
// baseline (640.496 us; speedup 1.0000x reference)
//
#include <hip/hip_runtime.h>
#include <hip/hip_bf16.h>

// Problem constants (match reference)
#define NNODES 100000
#define NEDGES 3200000
#define INDIM  512
#define HID    128
#define NCLS   64

// Bucketed CSR build
#define NBUCK  256
#define NPB    391                         // nodes per bucket; 256*391 = 100096
#define NCAP   (NBUCK * NPB)               // 100096
#define BCAP   16384                       // fixed padded capacity per bucket
#define CHUNK  8192
#define NCHUNKB ((NEDGES + CHUNK - 1) / CHUNK)   // 391 blocks

typedef __bf16 bf16x8 __attribute__((ext_vector_type(8)));
typedef float  f32x4  __attribute__((ext_vector_type(4)));

#define HPAD 136   // h0s row pad (272B stride, 16B-aligned)

// ---------------------------------------------------------------------------
// Fused: blocks 0..390 = per-chunk bucket histogram (reserve runs);
//        block 391     = weight transpose+bf16 convert (independent work).
// ---------------------------------------------------------------------------
__global__ __launch_bounds__(256)
void k_count_wcvt(const int* __restrict__ dst, int* __restrict__ gcnt,
                  int* __restrict__ my_base,
                  const float* __restrict__ W0, const float* __restrict__ W1,
                  __bf16* __restrict__ W0T, __bf16* __restrict__ W1T) {
  const int t = threadIdx.x;
  if (blockIdx.x == NCHUNKB) {
    for (int i = t; i < 65536; i += 256) {      // W0 [512][128] -> W0T[n][k]
      const int n = i >> 9, k = i & 511;
      W0T[i] = (__bf16)W0[k * HID + n];
    }
    for (int i = t; i < 8192; i += 256) {       // W1 [128][64] -> W1T[n][k]
      const int n = i >> 7, k = i & 127;
      W1T[i] = (__bf16)W1[k * NCLS + n];
    }
    return;
  }
  __shared__ int cnt[NBUCK];
  cnt[t] = 0;
  __syncthreads();
  const int base = blockIdx.x * CHUNK;
#pragma unroll
  for (int j = 0; j < CHUNK / 1024; ++j) {
    const int e = base + (j * 256 + t) * 4;
    if (e < NEDGES) {                           // NEDGES%4==0 => full int4 ok
      const int4 d = *(const int4*)&dst[e];
      atomicAdd(&cnt[(unsigned)d.x / NPB], 1);
      atomicAdd(&cnt[(unsigned)d.y / NPB], 1);
      atomicAdd(&cnt[(unsigned)d.z / NPB], 1);
      atomicAdd(&cnt[(unsigned)d.w / NPB], 1);
    }
  }
  __syncthreads();
  my_base[blockIdx.x * NBUCK + t] = atomicAdd(&gcnt[t], cnt[t]);
}

// ---------------------------------------------------------------------------
// Exclusive scan of bucket totals -> bsv segment bases.
// ---------------------------------------------------------------------------
__global__ void kA_bscan(const int* __restrict__ gcnt, int* __restrict__ bbase) {
  __shared__ int s[256];
  const int t = threadIdx.x;
  const int v = gcnt[t];
  s[t] = v;
  __syncthreads();
  for (int off = 1; off < 256; off <<= 1) {
    int x = (t >= off) ? s[t - off] : 0;
    __syncthreads();
    s[t] += x;
    __syncthreads();
  }
  bbase[t] = s[t] - v;
  if (t == 255) bbase[256] = s[255];            // == NEDGES
}

// ---------------------------------------------------------------------------
// Fused dispatch: blocks 0..390 = edge scatter into bucket runs (packs
// local-dst into src word: src | ldst<<17);  blocks 391.. = dense GEMM
// h1 = relu(X@W0)@W1 (bf16 MFMA). GEMM K-loop is BARRIER-FREE: B-fragments
// read straight from L2-resident W0T/W1T, A straight from feat. The only
// LDS use is the per-wave h0 relay (no block sync needed).
// ---------------------------------------------------------------------------
__global__ __launch_bounds__(256, 4)
void k_scatter_gemm(const int* __restrict__ dst, const int* __restrict__ src,
                    const float* __restrict__ val, const int* __restrict__ bbase,
                    const int* __restrict__ my_base, int2* __restrict__ bsv,
                    const float* __restrict__ feat, const __bf16* __restrict__ W0T,
                    const __bf16* __restrict__ W1T, __bf16* __restrict__ h1b) {
  __shared__ __align__(16) char smem[17408];
  const int tid = threadIdx.x;

  if (blockIdx.x < NCHUNKB) {
    // ---------------- scatter branch ----------------
    int* cur = (int*)smem;
    cur[tid] = bbase[tid] + my_base[blockIdx.x * NBUCK + tid];
    __syncthreads();
    const int base = blockIdx.x * CHUNK;
#pragma unroll
    for (int j = 0; j < CHUNK / 1024; ++j) {
      const int e = base + (j * 256 + tid) * 4;
      if (e < NEDGES) {
        const int4   d  = *(const int4*)&dst[e];
        const int4   sc = *(const int4*)&src[e];
        const float4 vv = *(const float4*)&val[e];
        int p, b, ld;
        b = (unsigned)d.x / NPB; ld = d.x - b * NPB;
        p = atomicAdd(&cur[b], 1);
        bsv[p] = make_int2(sc.x | (ld << 17), __float_as_int(vv.x));
        b = (unsigned)d.y / NPB; ld = d.y - b * NPB;
        p = atomicAdd(&cur[b], 1);
        bsv[p] = make_int2(sc.y | (ld << 17), __float_as_int(vv.y));
        b = (unsigned)d.z / NPB; ld = d.z - b * NPB;
        p = atomicAdd(&cur[b], 1);
        bsv[p] = make_int2(sc.z | (ld << 17), __float_as_int(vv.z));
        b = (unsigned)d.w / NPB; ld = d.w - b * NPB;
        p = atomicAdd(&cur[b], 1);
        bsv[p] = make_int2(sc.w | (ld << 17), __float_as_int(vv.w));
      }
    }
    return;
  }

  // ---------------- gemm branch (barrier-free K-loop) ----------------
  __bf16* h0s = (__bf16*)smem;                 // [64][136] = 17408 B, per-wave use

  const int wave = tid >> 6;
  const int lane = tid & 63;
  const int q    = lane >> 4;
  const int l16  = lane & 15;
  const int rb   = (blockIdx.x - NCHUNKB) * 64;

  int row = rb + wave * 16 + l16;
  if (row >= NNODES) row = NNODES - 1;          // clamped loads; stores guarded
  const float* __restrict__ arow = feat + (size_t)row * INDIM;
  // B row base for this lane: W0T[(t*16+l16)*512 + ...]
  const __bf16* __restrict__ b0 = W0T + (size_t)l16 * INDIM;

  f32x4 acc[8];
#pragma unroll
  for (int t = 0; t < 8; ++t) acc[t] = (f32x4){0.f, 0.f, 0.f, 0.f};

#pragma unroll 2
  for (int kk = 0; kk < INDIM / 32; ++kk) {
    const int k0 = kk * 32;
    const float4 a0 = *(const float4*)&arow[k0 + q * 8];
    const float4 a1 = *(const float4*)&arow[k0 + q * 8 + 4];
    bf16x8 aF;
    aF[0] = (__bf16)a0.x; aF[1] = (__bf16)a0.y; aF[2] = (__bf16)a0.z; aF[3] = (__bf16)a0.w;
    aF[4] = (__bf16)a1.x; aF[5] = (__bf16)a1.y; aF[6] = (__bf16)a1.z; aF[7] = (__bf16)a1.w;
#pragma unroll
    for (int t = 0; t < 8; ++t) {
      const bf16x8 bF = *(const bf16x8*)&b0[(size_t)t * 16 * INDIM + k0 + q * 8];
      acc[t] = __builtin_amdgcn_mfma_f32_16x16x32_bf16(aF, bF, acc[t], 0, 0, 0);
    }
  }

  // ReLU + cvt -> h0s in A-operand layout (C/D: row=q*4+j, col=l16)
#pragma unroll
  for (int t = 0; t < 8; ++t) {
#pragma unroll
    for (int j = 0; j < 4; ++j) {
      float v = acc[t][j];
      v = v > 0.f ? v : 0.f;
      h0s[(wave * 16 + q * 4 + j) * HPAD + t * 16 + l16] = (__bf16)v;
    }
  }
  // No barrier: each wave reads only its own 16-row h0s stripe.

  f32x4 acc2[4];
#pragma unroll
  for (int t = 0; t < 4; ++t) acc2[t] = (f32x4){0.f, 0.f, 0.f, 0.f};
#pragma unroll
  for (int kk = 0; kk < HID / 32; ++kk) {
    const bf16x8 aF = *(const bf16x8*)&h0s[(wave * 16 + l16) * HPAD + kk * 32 + q * 8];
#pragma unroll
    for (int t = 0; t < 4; ++t) {
      const bf16x8 bF = *(const bf16x8*)&W1T[(t * 16 + l16) * HID + kk * 32 + q * 8];
      acc2[t] = __builtin_amdgcn_mfma_f32_16x16x32_bf16(aF, bF, acc2[t], 0, 0, 0);
    }
  }

#pragma unroll
  for (int t = 0; t < 4; ++t) {
#pragma unroll
    for (int j = 0; j < 4; ++j) {
      const int grow = rb + wave * 16 + q * 4 + j;
      if (grow < NNODES)
        h1b[(size_t)grow * NCLS + t * 16 + l16] = (__bf16)acc2[t][j];
    }
  }
}

// ---------------------------------------------------------------------------
// Per-bucket CSR fill: degree histogram + padded scan (pad to 8) in LDS,
// rowinfo[w] = {base, pdeg}; writes confined to a 128KB region per block.
// ---------------------------------------------------------------------------
__global__ __launch_bounds__(256)
void kB3(const int2* __restrict__ bsv, const int* __restrict__ bbase,
         int2* __restrict__ rowinfo, int2* __restrict__ ecsr) {
  __shared__ int dl[NPB];
  __shared__ int cur[NPB];
  __shared__ int s[256];
  const int t = threadIdx.x;
  const int b = blockIdx.x;
  const int nb = b * NPB;
  for (int i = t; i < NPB; i += 256) dl[i] = 0;
  __syncthreads();
  const int beg = bbase[b], end = bbase[b + 1];
  for (int e = beg + t; e < end; e += 256)
    atomicAdd(&dl[((unsigned)bsv[e].x) >> 17], 1);
  __syncthreads();
  const int i0 = t * 2, i1 = t * 2 + 1;
  const int d0 = (i0 < NPB) ? dl[i0] : 0;
  const int d1 = (i1 < NPB) ? dl[i1] : 0;
  const int p0 = (d0 + 7) & ~7, p1 = (d1 + 7) & ~7;
  const int tsum = p0 + p1;
  s[t] = tsum;
  __syncthreads();
  for (int off = 1; off < 256; off <<= 1) {
    int x = (t >= off) ? s[t - off] : 0;
    __syncthreads();
    s[t] += x;
    __syncthreads();
  }
  const int excl = s[t] - tsum;
  const int gb = b * BCAP;
  const int2 z2 = make_int2(0, 0);
  if (i0 < NPB) {
    const int c = gb + excl;
    cur[i0] = c;
    if (nb + i0 < NNODES) rowinfo[nb + i0] = make_int2(c, p0);
    for (int k = d0; k < p0; ++k) ecsr[c + k] = z2;   // zero padding entries
  }
  if (i1 < NPB) {
    const int c = gb + excl + p0;
    cur[i1] = c;
    if (nb + i1 < NNODES) rowinfo[nb + i1] = make_int2(c, p1);
    for (int k = d1; k < p1; ++k) ecsr[c + k] = z2;
  }
  __syncthreads();
  for (int e = beg + t; e < end; e += 256) {
    const int2 sv = bsv[e];
    const int ld = ((unsigned)sv.x) >> 17;
    const int p = atomicAdd(&cur[ld], 1);             // LDS atomic
    ecsr[p] = make_int2(sv.x & 0x1FFFF, sv.y);
  }
}

// ---------------------------------------------------------------------------
// SpMM gather: one wave per dst row, lane = output column. Degree padded
// to 8 -> 8 independent 128B line-gathers in flight per iteration.
// ---------------------------------------------------------------------------
template <typename OUT_T>
__global__ __launch_bounds__(256, 8)
void k_spmm(const int2* __restrict__ rowinfo, const int2* __restrict__ ecsr,
            const __bf16* __restrict__ x, OUT_T* __restrict__ y) {
  const int wl   = (blockIdx.x * 256 + threadIdx.x) >> 6;
  const int w    = __builtin_amdgcn_readfirstlane(wl);   // 25000*4 waves = NNODES
  const int lane = threadIdx.x & 63;
  const int2 ri  = rowinfo[w];                           // {base, pdeg}
  const int base = ri.x, pdeg = ri.y;
  float acc = 0.f;
  for (int j = 0; j < pdeg; j += 8) {
    const int4 m0 = *(const int4*)&ecsr[base + j];
    const int4 m1 = *(const int4*)&ecsr[base + j + 2];
    const int4 m2 = *(const int4*)&ecsr[base + j + 4];
    const int4 m3 = *(const int4*)&ecsr[base + j + 6];
    const float x0 = (float)x[(size_t)m0.x * NCLS + lane];
    const float x1 = (float)x[(size_t)m0.z * NCLS + lane];
    const float x2 = (float)x[(size_t)m1.x * NCLS + lane];
    const float x3 = (float)x[(size_t)m1.z * NCLS + lane];
    const float x4 = (float)x[(size_t)m2.x * NCLS + lane];
    const float x5 = (float)x[(size_t)m2.z * NCLS + lane];
    const float x6 = (float)x[(size_t)m3.x * NCLS + lane];
    const float x7 = (float)x[(size_t)m3.z * NCLS + lane];
    acc += __int_as_float(m0.y) * x0;
    acc += __int_as_float(m0.w) * x1;
    acc += __int_as_float(m1.y) * x2;
    acc += __int_as_float(m1.w) * x3;
    acc += __int_as_float(m2.y) * x4;
    acc += __int_as_float(m2.w) * x5;
    acc += __int_as_float(m3.y) * x6;
    acc += __int_as_float(m3.w) * x7;
  }
  y[(size_t)w * NCLS + lane] = (OUT_T)acc;
}

// ---------------------------------------------------------------------------
extern "C" void kernel_launch(void* const* d_in, const int* in_sizes, int n_in,
                              void* d_out, int out_size, void* d_ws, size_t ws_size,
                              hipStream_t stream) {
  const float* feat = (const float*)d_in[0];
  const float* W0   = (const float*)d_in[1];
  const float* W1   = (const float*)d_in[2];
  const float* eval = (const float*)d_in[3];
  const int*   esrc = (const int*)d_in[4];
  const int*   edst = (const int*)d_in[5];
  float* out = (float*)d_out;

  // Workspace (~60.5 MB). bsv lives in d_out (exactly NEDGES int2 = 25.6 MB,
  // dead after kB3; final spmm overwrites d_out).
  char* p = (char*)d_ws;
  int2*   ecsr    = (int2*)p;   p += (size_t)NBUCK * BCAP * 8;  // 33,554,432
  int2*   rowinfo = (int2*)p;   p += (size_t)NCAP * 8;          // 800,768
  int*    my_base = (int*)p;    p += 400384;
  int*    gcnt    = (int*)p;    p += 1024;
  int*    bbase   = (int*)p;    p += 2048;
  __bf16* W0T     = (__bf16*)p; p += 131072;
  __bf16* W1T     = (__bf16*)p; p += 16384;
  __bf16* h1b     = (__bf16*)p; p += 12800000;
  __bf16* h2b     = (__bf16*)p; p += 12800000;
  int2*   bsv     = (int2*)d_out;                               // 25,600,000

  hipMemsetAsync(gcnt, 0, NBUCK * sizeof(int), stream);
  k_count_wcvt <<<NCHUNKB + 1, 256, 0, stream>>>(edst, gcnt, my_base,
                                                 W0, W1, W0T, W1T);
  kA_bscan     <<<1, 256, 0, stream>>>(gcnt, bbase);
  k_scatter_gemm<<<NCHUNKB + (NNODES + 63) / 64, 256, 0, stream>>>(
      edst, esrc, eval, bbase, my_base, bsv, feat, W0T, W1T, h1b);
  kB3          <<<NBUCK, 256, 0, stream>>>(bsv, bbase, rowinfo, ecsr);

  k_spmm<__bf16><<<NNODES / 4, 256, 0, stream>>>(rowinfo, ecsr, h1b, h2b);
  k_spmm<float> <<<NNODES / 4, 256, 0, stream>>>(rowinfo, ecsr, h2b, out);

  (void)in_sizes; (void)n_in; (void)out_size; (void)ws_size;
}

// Round 7
// 568.632 us; speedup vs baseline: 1.1264x; 1.1264x over previous
//
#include <hip/hip_runtime.h>
#include <hip/hip_bf16.h>

// Problem constants (match reference)
#define NNODES 100000
#define NEDGES 3200000
#define INDIM  512
#define HID    128
#define NCLS   64

// Bucketed CSR build
#define NBUCK  256
#define NPB    391                         // nodes per bucket; 256*391 = 100096
#define NCAP   (NBUCK * NPB)               // 100096
#define BCAP   16384                       // fixed padded capacity per bucket
#define CHUNK  8192
#define NCHUNKB ((NEDGES + CHUNK - 1) / CHUNK)   // 391 blocks

typedef __bf16 bf16x8 __attribute__((ext_vector_type(8)));
typedef float  f32x4  __attribute__((ext_vector_type(4)));

#define KPAD 520   // W0T LDS row stride (1040B = 16B-aligned; 260 words %32=4
                   // -> 8 lanes per 4-bank window = wave64-b128 optimal)
#define HPAD 136   // h0s row pad (272B stride; 68 words %32=4, same property)

// ---------------------------------------------------------------------------
// Fused: blocks 0..390 = per-chunk bucket histogram (reserve runs);
//        block 391     = weight transpose+bf16 convert (independent work).
// ---------------------------------------------------------------------------
__global__ __launch_bounds__(256)
void k_count_wcvt(const int* __restrict__ dst, int* __restrict__ gcnt,
                  int* __restrict__ my_base,
                  const float* __restrict__ W0, const float* __restrict__ W1,
                  __bf16* __restrict__ W0T, __bf16* __restrict__ W1T) {
  const int t = threadIdx.x;
  if (blockIdx.x == NCHUNKB) {
    for (int i = t; i < 65536; i += 256) {      // W0 [512][128] -> W0T[n][k]
      const int n = i >> 9, k = i & 511;
      W0T[i] = (__bf16)W0[k * HID + n];
    }
    for (int i = t; i < 8192; i += 256) {       // W1 [128][64] -> W1T[n][k]
      const int n = i >> 7, k = i & 127;
      W1T[i] = (__bf16)W1[k * NCLS + n];
    }
    return;
  }
  __shared__ int cnt[NBUCK];
  cnt[t] = 0;
  __syncthreads();
  const int base = blockIdx.x * CHUNK;
#pragma unroll
  for (int j = 0; j < CHUNK / 1024; ++j) {
    const int e = base + (j * 256 + t) * 4;
    if (e < NEDGES) {                           // NEDGES%4==0 => full int4 ok
      const int4 d = *(const int4*)&dst[e];
      atomicAdd(&cnt[(unsigned)d.x / NPB], 1);
      atomicAdd(&cnt[(unsigned)d.y / NPB], 1);
      atomicAdd(&cnt[(unsigned)d.z / NPB], 1);
      atomicAdd(&cnt[(unsigned)d.w / NPB], 1);
    }
  }
  __syncthreads();
  my_base[blockIdx.x * NBUCK + t] = atomicAdd(&gcnt[t], cnt[t]);
}

// ---------------------------------------------------------------------------
// Exclusive scan of bucket totals -> bsv segment bases.
// ---------------------------------------------------------------------------
__global__ void kA_bscan(const int* __restrict__ gcnt, int* __restrict__ bbase) {
  __shared__ int s[256];
  const int t = threadIdx.x;
  const int v = gcnt[t];
  s[t] = v;
  __syncthreads();
  for (int off = 1; off < 256; off <<= 1) {
    int x = (t >= off) ? s[t - off] : 0;
    __syncthreads();
    s[t] += x;
    __syncthreads();
  }
  bbase[t] = s[t] - v;
  if (t == 255) bbase[256] = s[255];            // == NEDGES
}

// ---------------------------------------------------------------------------
// Fused dispatch: blocks 0..390 = edge scatter into bucket runs;
// blocks 391.. = dense GEMM h1 = relu(X@W0)@W1 (bf16 MFMA).
// GEMM: ALL of W0T staged in LDS once (130KB, 1 block/CU), then a
// barrier-free K-loop (A from global, B from LDS, no re-staging).
// h0s relay aliases Bs after a single post-GEMM1 barrier.
// ---------------------------------------------------------------------------
__global__ __launch_bounds__(256, 1)
void k_scatter_gemm(const int* __restrict__ dst, const int* __restrict__ src,
                    const float* __restrict__ val, const int* __restrict__ bbase,
                    const int* __restrict__ my_base, int2* __restrict__ bsv,
                    const float* __restrict__ feat, const __bf16* __restrict__ W0T,
                    const __bf16* __restrict__ W1T, __bf16* __restrict__ h1b) {
  __shared__ __align__(16) char smem[HID * KPAD * 2];   // 133,120 B
  const int tid = threadIdx.x;

  if (blockIdx.x < NCHUNKB) {
    // ---------------- scatter branch ----------------
    int* cur = (int*)smem;
    cur[tid] = bbase[tid] + my_base[blockIdx.x * NBUCK + tid];
    __syncthreads();
    const int base = blockIdx.x * CHUNK;
#pragma unroll
    for (int j = 0; j < CHUNK / 1024; ++j) {
      const int e = base + (j * 256 + tid) * 4;
      if (e < NEDGES) {
        const int4   d  = *(const int4*)&dst[e];
        const int4   sc = *(const int4*)&src[e];
        const float4 vv = *(const float4*)&val[e];
        int p, b, ld;
        b = (unsigned)d.x / NPB; ld = d.x - b * NPB;
        p = atomicAdd(&cur[b], 1);
        bsv[p] = make_int2(sc.x | (ld << 17), __float_as_int(vv.x));
        b = (unsigned)d.y / NPB; ld = d.y - b * NPB;
        p = atomicAdd(&cur[b], 1);
        bsv[p] = make_int2(sc.y | (ld << 17), __float_as_int(vv.y));
        b = (unsigned)d.z / NPB; ld = d.z - b * NPB;
        p = atomicAdd(&cur[b], 1);
        bsv[p] = make_int2(sc.z | (ld << 17), __float_as_int(vv.z));
        b = (unsigned)d.w / NPB; ld = d.w - b * NPB;
        p = atomicAdd(&cur[b], 1);
        bsv[p] = make_int2(sc.w | (ld << 17), __float_as_int(vv.w));
      }
    }
    return;
  }

  // ---------------- gemm branch ----------------
  __bf16* Bs  = (__bf16*)smem;                 // [128][KPAD] full W0T
  __bf16* h0s = (__bf16*)smem;                 // aliases Bs after barrier #2

  const int wave = tid >> 6;
  const int lane = tid & 63;
  const int q    = lane >> 4;
  const int l16  = lane & 15;
  const int rb   = (blockIdx.x - NCHUNKB) * 64;

  // Stage ALL of W0T: 8192 bf16x8 chunks, 32 per thread. Coalesced.
#pragma unroll
  for (int i = 0; i < 32; ++i) {
    const int c  = tid + i * 256;
    const int n  = c >> 6;                     // 64 chunks per 512-elem row
    const int ko = (c & 63) * 8;
    *(bf16x8*)&Bs[n * KPAD + ko] = *(const bf16x8*)&W0T[n * INDIM + ko];
  }

  int row = rb + wave * 16 + l16;
  if (row >= NNODES) row = NNODES - 1;          // clamped loads; stores guarded
  const float* __restrict__ arow = feat + (size_t)row * INDIM;

  f32x4 acc[8];
#pragma unroll
  for (int t = 0; t < 8; ++t) acc[t] = (f32x4){0.f, 0.f, 0.f, 0.f};

  __syncthreads();                              // Bs ready

#pragma unroll 4
  for (int kk = 0; kk < INDIM / 32; ++kk) {
    const int k0 = kk * 32;
    const float4 a0 = *(const float4*)&arow[k0 + q * 8];
    const float4 a1 = *(const float4*)&arow[k0 + q * 8 + 4];
    bf16x8 aF;
    aF[0] = (__bf16)a0.x; aF[1] = (__bf16)a0.y; aF[2] = (__bf16)a0.z; aF[3] = (__bf16)a0.w;
    aF[4] = (__bf16)a1.x; aF[5] = (__bf16)a1.y; aF[6] = (__bf16)a1.z; aF[7] = (__bf16)a1.w;
#pragma unroll
    for (int t = 0; t < 8; ++t) {
      const bf16x8 bF = *(const bf16x8*)&Bs[(t * 16 + l16) * KPAD + k0 + q * 8];
      acc[t] = __builtin_amdgcn_mfma_f32_16x16x32_bf16(aF, bF, acc[t], 0, 0, 0);
    }
  }

  __syncthreads();                              // all waves done reading Bs

  // ReLU + cvt -> h0s (aliases Bs) in A-operand layout (C/D: row=q*4+j, col=l16)
#pragma unroll
  for (int t = 0; t < 8; ++t) {
#pragma unroll
    for (int j = 0; j < 4; ++j) {
      float v = acc[t][j];
      v = v > 0.f ? v : 0.f;
      h0s[(wave * 16 + q * 4 + j) * HPAD + t * 16 + l16] = (__bf16)v;
    }
  }
  // No barrier: each wave reads only its own 16-row h0s stripe.

  f32x4 acc2[4];
#pragma unroll
  for (int t = 0; t < 4; ++t) acc2[t] = (f32x4){0.f, 0.f, 0.f, 0.f};
#pragma unroll
  for (int kk = 0; kk < HID / 32; ++kk) {
    const bf16x8 aF = *(const bf16x8*)&h0s[(wave * 16 + l16) * HPAD + kk * 32 + q * 8];
#pragma unroll
    for (int t = 0; t < 4; ++t) {
      const bf16x8 bF = *(const bf16x8*)&W1T[(t * 16 + l16) * HID + kk * 32 + q * 8];
      acc2[t] = __builtin_amdgcn_mfma_f32_16x16x32_bf16(aF, bF, acc2[t], 0, 0, 0);
    }
  }

#pragma unroll
  for (int t = 0; t < 4; ++t) {
#pragma unroll
    for (int j = 0; j < 4; ++j) {
      const int grow = rb + wave * 16 + q * 4 + j;
      if (grow < NNODES)
        h1b[(size_t)grow * NCLS + t * 16 + l16] = (__bf16)acc2[t][j];
    }
  }
}

// ---------------------------------------------------------------------------
// Per-bucket CSR fill: degree histogram + padded scan (pad to 8) in LDS,
// rowinfo[w] = {base, pdeg}; writes confined to a 128KB region per block.
// ---------------------------------------------------------------------------
__global__ __launch_bounds__(256)
void kB3(const int2* __restrict__ bsv, const int* __restrict__ bbase,
         int2* __restrict__ rowinfo, int2* __restrict__ ecsr) {
  __shared__ int dl[NPB];
  __shared__ int cur[NPB];
  __shared__ int s[256];
  const int t = threadIdx.x;
  const int b = blockIdx.x;
  const int nb = b * NPB;
  for (int i = t; i < NPB; i += 256) dl[i] = 0;
  __syncthreads();
  const int beg = bbase[b], end = bbase[b + 1];
  for (int e = beg + t; e < end; e += 256)
    atomicAdd(&dl[((unsigned)bsv[e].x) >> 17], 1);
  __syncthreads();
  const int i0 = t * 2, i1 = t * 2 + 1;
  const int d0 = (i0 < NPB) ? dl[i0] : 0;
  const int d1 = (i1 < NPB) ? dl[i1] : 0;
  const int p0 = (d0 + 7) & ~7, p1 = (d1 + 7) & ~7;
  const int tsum = p0 + p1;
  s[t] = tsum;
  __syncthreads();
  for (int off = 1; off < 256; off <<= 1) {
    int x = (t >= off) ? s[t - off] : 0;
    __syncthreads();
    s[t] += x;
    __syncthreads();
  }
  const int excl = s[t] - tsum;
  const int gb = b * BCAP;
  const int2 z2 = make_int2(0, 0);
  if (i0 < NPB) {
    const int c = gb + excl;
    cur[i0] = c;
    if (nb + i0 < NNODES) rowinfo[nb + i0] = make_int2(c, p0);
    for (int k = d0; k < p0; ++k) ecsr[c + k] = z2;   // zero padding entries
  }
  if (i1 < NPB) {
    const int c = gb + excl + p0;
    cur[i1] = c;
    if (nb + i1 < NNODES) rowinfo[nb + i1] = make_int2(c, p1);
    for (int k = d1; k < p1; ++k) ecsr[c + k] = z2;
  }
  __syncthreads();
  for (int e = beg + t; e < end; e += 256) {
    const int2 sv = bsv[e];
    const int ld = ((unsigned)sv.x) >> 17;
    const int p = atomicAdd(&cur[ld], 1);             // LDS atomic
    ecsr[p] = make_int2(sv.x & 0x1FFFF, sv.y);
  }
}

// ---------------------------------------------------------------------------
// SpMM gather: one wave per dst row, lane = output column. Degree padded
// to 8 -> 8 independent 128B line-gathers in flight per iteration.
// ---------------------------------------------------------------------------
template <typename OUT_T>
__global__ __launch_bounds__(256, 8)
void k_spmm(const int2* __restrict__ rowinfo, const int2* __restrict__ ecsr,
            const __bf16* __restrict__ x, OUT_T* __restrict__ y) {
  const int wl   = (blockIdx.x * 256 + threadIdx.x) >> 6;
  const int w    = __builtin_amdgcn_readfirstlane(wl);   // 25000*4 waves = NNODES
  const int lane = threadIdx.x & 63;
  const int2 ri  = rowinfo[w];                           // {base, pdeg}
  const int base = ri.x, pdeg = ri.y;
  float acc = 0.f;
  for (int j = 0; j < pdeg; j += 8) {
    const int4 m0 = *(const int4*)&ecsr[base + j];
    const int4 m1 = *(const int4*)&ecsr[base + j + 2];
    const int4 m2 = *(const int4*)&ecsr[base + j + 4];
    const int4 m3 = *(const int4*)&ecsr[base + j + 6];
    const float x0 = (float)x[(size_t)m0.x * NCLS + lane];
    const float x1 = (float)x[(size_t)m0.z * NCLS + lane];
    const float x2 = (float)x[(size_t)m1.x * NCLS + lane];
    const float x3 = (float)x[(size_t)m1.z * NCLS + lane];
    const float x4 = (float)x[(size_t)m2.x * NCLS + lane];
    const float x5 = (float)x[(size_t)m2.z * NCLS + lane];
    const float x6 = (float)x[(size_t)m3.x * NCLS + lane];
    const float x7 = (float)x[(size_t)m3.z * NCLS + lane];
    acc += __int_as_float(m0.y) * x0;
    acc += __int_as_float(m0.w) * x1;
    acc += __int_as_float(m1.y) * x2;
    acc += __int_as_float(m1.w) * x3;
    acc += __int_as_float(m2.y) * x4;
    acc += __int_as_float(m2.w) * x5;
    acc += __int_as_float(m3.y) * x6;
    acc += __int_as_float(m3.w) * x7;
  }
  y[(size_t)w * NCLS + lane] = (OUT_T)acc;
}

// ---------------------------------------------------------------------------
extern "C" void kernel_launch(void* const* d_in, const int* in_sizes, int n_in,
                              void* d_out, int out_size, void* d_ws, size_t ws_size,
                              hipStream_t stream) {
  const float* feat = (const float*)d_in[0];
  const float* W0   = (const float*)d_in[1];
  const float* W1   = (const float*)d_in[2];
  const float* eval = (const float*)d_in[3];
  const int*   esrc = (const int*)d_in[4];
  const int*   edst = (const int*)d_in[5];
  float* out = (float*)d_out;

  // Workspace (~60.5 MB). bsv lives in d_out (exactly NEDGES int2 = 25.6 MB,
  // dead after kB3; final spmm overwrites d_out).
  char* p = (char*)d_ws;
  int2*   ecsr    = (int2*)p;   p += (size_t)NBUCK * BCAP * 8;  // 33,554,432
  int2*   rowinfo = (int2*)p;   p += (size_t)NCAP * 8;          // 800,768
  int*    my_base = (int*)p;    p += 400384;
  int*    gcnt    = (int*)p;    p += 1024;
  int*    bbase   = (int*)p;    p += 2048;
  __bf16* W0T     = (__bf16*)p; p += 131072;
  __bf16* W1T     = (__bf16*)p; p += 16384;
  __bf16* h1b     = (__bf16*)p; p += 12800000;
  __bf16* h2b     = (__bf16*)p; p += 12800000;
  int2*   bsv     = (int2*)d_out;                               // 25,600,000

  hipMemsetAsync(gcnt, 0, NBUCK * sizeof(int), stream);
  k_count_wcvt <<<NCHUNKB + 1, 256, 0, stream>>>(edst, gcnt, my_base,
                                                 W0, W1, W0T, W1T);
  kA_bscan     <<<1, 256, 0, stream>>>(gcnt, bbase);
  k_scatter_gemm<<<NCHUNKB + (NNODES + 63) / 64, 256, 0, stream>>>(
      edst, esrc, eval, bbase, my_base, bsv, feat, W0T, W1T, h1b);
  kB3          <<<NBUCK, 256, 0, stream>>>(bsv, bbase, rowinfo, ecsr);

  k_spmm<__bf16><<<NNODES / 4, 256, 0, stream>>>(rowinfo, ecsr, h1b, h2b);
  k_spmm<float> <<<NNODES / 4, 256, 0, stream>>>(rowinfo, ecsr, h2b, out);

  (void)in_sizes; (void)n_in; (void)out_size; (void)ws_size;
}